// Round 5
// baseline (6795.415 us; speedup 1.0000x reference)
//
#include <hip/hip_runtime.h>
#include <cmath>

constexpr int SEQ = 64;    // sequence length
constexpr int NB  = 128;   // batch
constexpr int H   = 256;   // hidden
constexpr int DIN = 128;   // composed token dim
constexpr int DE  = 256;   // word emb dim
constexpr int NA  = 64;    // actions
constexpr int S1  = 41;    // STACK_SIZE+1
constexpr int MS  = 100;   // max steps
constexpr int G4  = 1024;  // 4*H

__device__ __forceinline__ float sigf(float x){ return 1.0f/(1.0f+expf(-x)); }

// ---------------- transpose: in [R][C] -> out [C][R]
__global__ void transpose_k(const float* __restrict__ in, float* __restrict__ out,
                            int R, int C){
  __shared__ float t[32][33];
  int bx = blockIdx.x*32, by = blockIdx.y*32;
  int x = threadIdx.x, y = threadIdx.y;   // block 32x8
  #pragma unroll
  for (int j = 0; j < 32; j += 8)
    t[y+j][x] = in[(size_t)(by+y+j)*C + bx + x];
  __syncthreads();
  #pragma unroll
  for (int j = 0; j < 32; j += 8)
    out[(size_t)(bx+y+j)*R + by + x] = t[x][y+j];
}

__global__ void hist_proj_kernel(const float* __restrict__ Wih,
                                 const float* __restrict__ bih,
                                 const float* __restrict__ bhh,
                                 const float* __restrict__ aemb,
                                 float* __restrict__ out){
  int a = blockIdx.x, t = threadIdx.x;
  __shared__ float e[64];
  if (t < 64) e[t] = aemb[a*64 + t];
  __syncthreads();
  for (int r = t; r < G4; r += blockDim.x){
    const float* w = Wih + r*64;
    float acc = bih[r] + bhh[r];
    #pragma unroll
    for (int k = 0; k < 64; k += 4)
      acc += w[k]*e[k] + w[k+1]*e[k+1] + w[k+2]*e[k+2] + w[k+3]*e[k+3];
    out[a*G4 + r] = acc;
  }
}

// f32 stream: 256 rows x (1024-col float4 slice), depth-8 two-buffer prefetch.
// FMA order strictly c-ascending per accumulator (bit-stable vs prior rounds).
__device__ __forceinline__ void stream256(const float4* __restrict__ W, int lane,
                                          const float* __restrict__ xb,
                                          float* __restrict__ acc){
  float4 A[8], B[8];
  #pragma unroll
  for (int j = 0; j < 8; ++j) A[j] = W[(size_t)j*256 + lane];
  for (int cb = 0; cb < 256; cb += 16){
    #pragma unroll
    for (int j = 0; j < 8; ++j) B[j] = W[(size_t)((cb+8+j)&255)*256 + lane];
    #pragma unroll
    for (int j = 0; j < 8; ++j){ float x = xb[cb+j];
      acc[0]+=A[j].x*x; acc[1]+=A[j].y*x; acc[2]+=A[j].z*x; acc[3]+=A[j].w*x; }
    #pragma unroll
    for (int j = 0; j < 8; ++j) A[j] = W[(size_t)((cb+16+j)&255)*256 + lane];
    #pragma unroll
    for (int j = 0; j < 8; ++j){ float x = xb[cb+8+j];
      acc[0]+=B[j].x*x; acc[1]+=B[j].y*x; acc[2]+=B[j].z*x; acc[3]+=B[j].w*x; }
  }
}

// f32 stream: 128 rows starting at base (for P1 c-split).
__device__ __forceinline__ void stream128(const float4* __restrict__ W, int base, int lane,
                                          const float* __restrict__ xb,
                                          float* __restrict__ acc){
  float4 A[8], B[8];
  #pragma unroll
  for (int j = 0; j < 8; ++j) A[j] = W[(size_t)(base+j)*256 + lane];
  for (int cb = 0; cb < 128; cb += 16){
    #pragma unroll
    for (int j = 0; j < 8; ++j) B[j] = W[(size_t)(base+((cb+8+j)&127))*256 + lane];
    #pragma unroll
    for (int j = 0; j < 8; ++j){ float x = xb[base+cb+j];
      acc[0]+=A[j].x*x; acc[1]+=A[j].y*x; acc[2]+=A[j].z*x; acc[3]+=A[j].w*x; }
    #pragma unroll
    for (int j = 0; j < 8; ++j) A[j] = W[(size_t)(base+((cb+16+j)&127))*256 + lane];
    #pragma unroll
    for (int j = 0; j < 8; ++j){ float x = xb[base+cb+8+j];
      acc[0]+=B[j].x*x; acc[1]+=B[j].y*x; acc[2]+=B[j].z*x; acc[3]+=B[j].w*x; }
  }
}

// f64 summary block: 64 rows (row0 + sg*64 ..), 256-col float4 slice (lane<64).
__device__ __forceinline__ void sumblk(const float4* __restrict__ W, int row0, int sg,
                                       int lane, const float* __restrict__ xb,
                                       double* __restrict__ a){
  float4 A[8], B[8];
  const int base = row0 + sg*64;
  #pragma unroll
  for (int j = 0; j < 8; ++j) A[j] = W[(size_t)(base+j)*64 + lane];
  for (int cb = 0; cb < 64; cb += 16){
    #pragma unroll
    for (int j = 0; j < 8; ++j) B[j] = W[(size_t)(base+((cb+8+j)&63))*64 + lane];
    #pragma unroll
    for (int j = 0; j < 8; ++j){ double x = (double)xb[sg*64+cb+j];
      a[0]+=(double)A[j].x*x; a[1]+=(double)A[j].y*x;
      a[2]+=(double)A[j].z*x; a[3]+=(double)A[j].w*x; }
    #pragma unroll
    for (int j = 0; j < 8; ++j) A[j] = W[(size_t)(base+((cb+16+j)&63))*64 + lane];
    #pragma unroll
    for (int j = 0; j < 8; ++j){ double x = (double)xb[sg*64+cb+8+j];
      a[0]+=(double)B[j].x*x; a[1]+=(double)B[j].y*x;
      a[2]+=(double)B[j].z*x; a[3]+=(double)B[j].w*x; }
  }
}

// One workgroup (512 threads) per batch element. Per-level product caches
// (exact recompute values) skip the stack/bstate streams on non-push steps.
__global__ __launch_bounds__(512, 2)
void parser_kernel(const int* __restrict__ tokens,
                   const float* __restrict__ word_emb,
                   const float* __restrict__ Wt_cmp,   // [256][128]
                   const float* __restrict__ compose_b,
                   const float* __restrict__ h0,
                   const float* __restrict__ c0,
                   const float* __restrict__ Wt_pbih,  // [128][1024]
                   const float* __restrict__ Wt_pb,    // [256][1024]
                   const float* __restrict__ pb_bih,
                   const float* __restrict__ pb_bhh,
                   const float* __restrict__ Wt_stih,  // [128][1024]
                   const float* __restrict__ Wt_st,    // [256][1024]
                   const float* __restrict__ st_bih,
                   const float* __restrict__ st_bhh,
                   const float* __restrict__ Wt_hi,    // [256][1024]
                   const float* __restrict__ Wt_sum,   // [768][256]
                   const float* __restrict__ sum_b,
                   const float* __restrict__ Wt_act,   // [256][64]
                   const float* __restrict__ act_b,
                   const int* __restrict__ stack_map,
                   const int* __restrict__ buffer_map,
                   const float* __restrict__ histxz,   // [64][1024]
                   float* __restrict__ pb_zx,   // [B][64][1024] (P0/P1 only)
                   float* __restrict__ stzc,    // aliases pb_zx: [B][41][1024]
                   double* __restrict__ sumsc,  // aliases pb_zx tail: [B][41][256]
                   float* __restrict__ st_zx,   // [B][65][1024]
                   float* __restrict__ bufh,    // [B][64][256]
                   float* __restrict__ scst,    // [B][41][256] stack c
                   float* __restrict__ sth_g,   // [B][41][256] stack h
                   float* __restrict__ out)     // [100][128][64]
{
  __shared__ __align__(16) float U[10240];   // P0: tokl[64][128]+embs[8][256]; main: pdA[3][4][256]f64 / pdL
  __shared__ __align__(16) float u1[2048];   // z_st/z_hi | blkA/blkS (f64)
  __shared__ __align__(16) double blkB[256]; // bstate summary block (persistent)
  __shared__ __align__(16) float stop[H];    // stack-top h
  __shared__ __align__(16) float bstate[H];
  __shared__ __align__(16) float ahl[H];
  __shared__ __align__(16) float acl[H];
  __shared__ __align__(16) float h0l[H];
  __shared__ int validArr[48];
  __shared__ int ctl[16];

  const int b   = blockIdx.x;
  const int tid = threadIdx.x;

  float* tokl = U;               // [64][128]
  float* embs = U + SEQ*DIN;     // [8][256]

  if (tid < H) h0l[tid] = h0[tid];
  __syncthreads();

  // ---------------- P0a: tok[t] = relu(W_c @ emb[tokens[t,b]] + b_c)
  {
    const int d = tid & 127, tb = tid >> 7;    // tb 0..3 -> tokens tb, tb+4
    const float cb_ = compose_b[d];
    for (int pass = 0; pass < 8; ++pass){
      {
        int l = tid & 255, r0 = (tid >> 8)*4;
        #pragma unroll
        for (int j = 0; j < 4; ++j){
          int row = r0 + j;
          embs[row*DE + l] = word_emb[(size_t)tokens[(pass*8+row)*NB + b]*DE + l];
        }
      }
      __syncthreads();
      float a0 = 0.f, a1 = 0.f;
      const float* e0 = embs + tb*DE;
      const float* e1 = embs + (tb+4)*DE;
      for (int c = 0; c < DE; ++c){
        float w = Wt_cmp[c*DIN + d];
        a0 += w*e0[c]; a1 += w*e1[c];
      }
      tokl[(pass*8 + tb    )*DIN + d] = fmaxf(a0 + cb_, 0.f);
      tokl[(pass*8 + tb + 4)*DIN + d] = fmaxf(a1 + cb_, 0.f);
      __syncthreads();
    }
  }

  // ---------------- P0b: zx = Wih @ tok + (bih+bhh)
  {
    const int m = tid >> 8, lt = tid & 255;
    const float* Wt = m ? Wt_stih : Wt_pbih;
    float* zxb = m ? (st_zx + (size_t)b*(SEQ+1)*G4) : (pb_zx + (size_t)b*SEQ*G4);
    const float* bA = m ? st_bih : pb_bih;
    const float* bB = m ? st_bhh : pb_bhh;
    float4 x1 = ((const float4*)bA)[lt], x2 = ((const float4*)bB)[lt];
    float bx = x1.x + x2.x, by = x1.y + x2.y, bz = x1.z + x2.z, bw = x1.w + x2.w;
    for (int blk = 0; blk < 4; ++blk){
      float ax[16], ay[16], az[16], aw[16];
      #pragma unroll
      for (int t = 0; t < 16; ++t){ ax[t]=0.f; ay[t]=0.f; az[t]=0.f; aw[t]=0.f; }
      const float* tb = tokl + (blk*16)*DIN;
      for (int c = 0; c < DIN; ++c){
        float4 w = ((const float4*)(Wt + (size_t)c*G4))[lt];
        #pragma unroll
        for (int t = 0; t < 16; ++t){
          float x = tb[t*DIN + c];
          ax[t] += w.x*x; ay[t] += w.y*x; az[t] += w.z*x; aw[t] += w.w*x;
        }
      }
      #pragma unroll
      for (int t = 0; t < 16; ++t)
        ((float4*)(zxb + (size_t)(blk*16 + t)*G4))[lt] =
            make_float4(ax[t]+bx, ay[t]+by, az[t]+bz, aw[t]+bw);
    }
    if (m) ((float4*)(zxb + (size_t)SEQ*G4))[lt] = make_float4(bx, by, bz, bw);
  }
  __syncthreads();

  // ---------------- P1: pre-buffer LSTM over reversed tokens
  float cpb = 0.f;
  if (tid < H){ ahl[tid] = h0l[tid]; cpb = c0[tid]; }
  __syncthreads();
  for (int k = 0; k < SEQ; ++k){
    const int tt = SEQ - 1 - k;
    {
      const int g = tid >> 8, lt = tid & 255;
      float acc[4] = {0.f,0.f,0.f,0.f};
      stream128((const float4*)Wt_pb, g*128, lt, ahl, acc);
      if (g == 0){
        float4 zx = ((const float4*)(pb_zx + ((size_t)b*SEQ + tt)*G4))[lt];
        acc[0]+=zx.x; acc[1]+=zx.y; acc[2]+=zx.z; acc[3]+=zx.w;
      }
      *(float4*)(u1 + g*1024 + 4*lt) = make_float4(acc[0],acc[1],acc[2],acc[3]);
    }
    __syncthreads();
    if (tid < H){
      float zi = u1[tid]       + u1[1024 + tid];
      float zf = u1[256 + tid] + u1[1024 + 256 + tid];
      float zg = u1[512 + tid] + u1[1024 + 512 + tid];
      float zo = u1[768 + tid] + u1[1024 + 768 + tid];
      float c2 = sigf(zf)*cpb + sigf(zi)*tanhf(zg);
      float h2 = sigf(zo)*tanhf(c2);
      cpb = c2;
      ahl[tid] = h2;
      bufh[((size_t)b*SEQ + k)*H + tid] = h2;
    }
    __syncthreads();
  }

  // ---------------- main init
  if (tid < H) bstate[tid] = ahl[tid];         // b_state = buf_h[63]
  __syncthreads();
  if (tid < H){
    ahl[tid] = h0l[tid]; acl[tid] = c0[tid]; stop[tid] = h0l[tid];
    sth_g[(size_t)b*S1*H + tid] = h0l[tid];
    scst [(size_t)b*S1*H + tid] = c0[tid];
  }
  if (tid < 48) validArr[tid] = 0;
  if (tid == 0){ ctl[0]=0; ctl[1]=SEQ; ctl[2]=SEQ-1; ctl[10]=1; ctl[11]=1; }
  __syncthreads();

  const float4* Wsum4 = (const float4*)Wt_sum;
  double* pdA = (double*)U;       // [3][4][256]
  double* blkA = (double*)u1;     // [256]
  double* blkS = blkA + 256;      // [256]

  // ---------------- main parser loop
  for (int step = 0; step < MS; ++step){
    const int spos = ctl[0], bposc = ctl[1], sinc = ctl[2];
    const int ns = ctl[10], nb = ctl[11];

    // A1: summary block streams (f64 partials). slot0=ah always; slot1=stack
    // if ns; slot2=bstate if nb (g1, or g0-second when ns&&nb).
    {
      const int g = tid >> 8, idx = tid & 255, sg = idx >> 6, lane = idx & 63;
      if (g == 0){
        double a[4] = {0,0,0,0};
        sumblk(Wsum4, 512, sg, lane, ahl, a);
        #pragma unroll
        for (int k2 = 0; k2 < 4; ++k2) pdA[0*1024 + sg*256 + 4*lane + k2] = a[k2];
        if (ns && nb){
          double a2[4] = {0,0,0,0};
          sumblk(Wsum4, 256, sg, lane, bstate, a2);
          #pragma unroll
          for (int k2 = 0; k2 < 4; ++k2) pdA[2*1024 + sg*256 + 4*lane + k2] = a2[k2];
        }
      } else {
        if (ns){
          double a[4] = {0,0,0,0};
          sumblk(Wsum4, 0, sg, lane, stop, a);
          #pragma unroll
          for (int k2 = 0; k2 < 4; ++k2) pdA[1*1024 + sg*256 + 4*lane + k2] = a[k2];
        } else if (nb){
          double a[4] = {0,0,0,0};
          sumblk(Wsum4, 256, sg, lane, bstate, a);
          #pragma unroll
          for (int k2 = 0; k2 < 4; ++k2) pdA[2*1024 + sg*256 + 4*lane + k2] = a[k2];
        }
      }
    }
    __syncthreads();

    // A2: reduce partials into blkA/blkS/blkB; stack-block cache I/O.
    {
      const int col = tid & 255;
      if (tid < 256){
        double s = pdA[col];
        s += pdA[256 + col]; s += pdA[512 + col]; s += pdA[768 + col];
        blkA[col] = s;
      } else {
        double* srow = sumsc + ((size_t)b*S1 + spos)*H;
        if (ns){
          double s = pdA[1024 + col];
          s += pdA[1024 + 256 + col]; s += pdA[1024 + 512 + col]; s += pdA[1024 + 768 + col];
          blkS[col] = s; srow[col] = s;
        } else {
          blkS[col] = srow[col];
        }
        if (nb){
          double s = pdA[2048 + col];
          s += pdA[2048 + 256 + col]; s += pdA[2048 + 512 + col]; s += pdA[2048 + 768 + col];
          blkB[col] = s;
        }
      }
    }
    __syncthreads();

    // C1: summary (inline, f64) + logits partials (8-way c-split)
    {
      const int col = tid & 63, cg = tid >> 6;
      double acc = 0.0;
      for (int c = cg*32; c < cg*32 + 32; ++c){
        double sm = blkA[c] + blkS[c] + blkB[c] + (double)sum_b[c];
        float smf = fmaxf((float)sm, 0.f);
        acc += (double)Wt_act[(size_t)c*NA + col] * (double)smf;
      }
      pdA[cg*64 + col] = acc;   // pdA region reused as pdL
    }
    __syncthreads();

    // CD: wave0 does softmax/argmax/control; ALL threads then run z-streams.
    if (tid < NA){
      double s = (double)act_b[tid];
      #pragma unroll
      for (int q = 0; q < 8; ++q) s += pdA[q*64 + tid];
      float v = (float)s;
      float mx = v;
      #pragma unroll
      for (int o = 32; o > 0; o >>= 1) mx = fmaxf(mx, __shfl_xor(mx, o));
      float ex = expf(v - mx), sm = ex;
      #pragma unroll
      for (int o = 32; o > 0; o >>= 1) sm += __shfl_xor(sm, o);
      out[(((size_t)step*NB) + b)*NA + tid] = v - mx - logf(sm);
      float bv = v; int bi = tid;
      #pragma unroll
      for (int o = 32; o > 0; o >>= 1){
        float ov = __shfl_xor(bv, o); int oi = __shfl_xor(bi, o);
        if (ov > bv || (ov == bv && oi < bi)){ bv = ov; bi = oi; }
      }
      if (tid == 0){
        int a = bi;
        int sop = stack_map[a], bop = buffer_map[a];
        if (spos == 0 && sop == -1) sop = 0;
        if (spos >= S1 - 1 && sop == 1) sop = 0;
        if (bposc == 0 && bop == -1) bop = 0;
        int push  = (sop == 1) ? 1 : 0;
        int widx  = (spos + 1 < S1 - 1) ? spos + 1 : S1 - 1;
        int sposn = spos + sop;
        int bposn = bposc + bop;
        int ne    = (bposn > 0) ? 1 : 0;
        int gidx  = bposn - 1; if (gidx < 0) gidx = 0; if (gidx > SEQ - 1) gidx = SEQ - 1;
        ctl[3]=a; ctl[4]=push; ctl[5]=widx; ctl[6]=sposn;
        ctl[7]=bposn; ctl[8]=ne; ctl[9]=gidx; ctl[12]=bop;
      }
    }
    {
      const int gD = tid >> 8, lt = tid & 255;
      if (gD == 0){
        float4 zxr = ((const float4*)(st_zx + ((size_t)b*(SEQ+1) + sinc)*G4))[lt];
        float* srow = stzc + ((size_t)b*S1 + spos)*G4;
        float4 zv;
        if (ns){
          float acc[4] = {0.f,0.f,0.f,0.f};
          stream256((const float4*)Wt_st, lt, stop, acc);
          ((float4*)srow)[lt] = make_float4(acc[0],acc[1],acc[2],acc[3]);
          zv = make_float4(acc[0]+zxr.x, acc[1]+zxr.y, acc[2]+zxr.z, acc[3]+zxr.w);
        } else {
          float4 p = ((const float4*)srow)[lt];
          zv = make_float4(p.x+zxr.x, p.y+zxr.y, p.z+zxr.z, p.w+zxr.w);
        }
        *(float4*)(u1 + 4*lt) = zv;
      } else {
        float acc[4] = {0.f,0.f,0.f,0.f};
        stream256((const float4*)Wt_hi, lt, ahl, acc);
        *(float4*)(u1 + 1024 + 4*lt) = make_float4(acc[0],acc[1],acc[2],acc[3]);
      }
    }
    __syncthreads();

    // E: gates + commit + flag bookkeeping
    {
      const int a = ctl[3], push = ctl[4], widx = ctl[5], sposn = ctl[6];
      const int ne = ctl[8], gidx = ctl[9], bch = ctl[12];
      if (tid < H){
        float zi = u1[tid], zf = u1[256+tid], zg = u1[512+tid], zo = u1[768+tid];
        float cold = scst[((size_t)b*S1 + spos)*H + tid];
        float c2 = sigf(zf)*cold + sigf(zi)*tanhf(zg);
        float h2 = sigf(zo)*tanhf(c2);
        if (push){
          stop[tid] = h2;
          sth_g[((size_t)b*S1 + widx)*H + tid] = h2;
          scst [((size_t)b*S1 + widx)*H + tid] = c2;
        } else if (sposn != spos){
          stop[tid] = sth_g[((size_t)b*S1 + sposn)*H + tid];
        }
      } else {
        const int u2 = tid - H;
        const float* hx = histxz + (size_t)a*G4;
        float zi = u1[1024 +        u2] + hx[       u2];
        float zf = u1[1024 + 256 +  u2] + hx[256 +  u2];
        float zg = u1[1024 + 512 +  u2] + hx[512 +  u2];
        float zo = u1[1024 + 768 +  u2] + hx[768 +  u2];
        float c2 = sigf(zf)*acl[u2] + sigf(zi)*tanhf(zg);
        float h2 = sigf(zo)*tanhf(c2);
        acl[u2] = c2; ahl[u2] = h2;
        if (bch != 0)
          bstate[u2] = ne ? bufh[((size_t)b*SEQ + gidx)*H + u2] : h0l[u2];
      }
      if (tid == 0){
        if (ns) validArr[spos] = 1;
        if (push) validArr[widx] = 0;
        ctl[0] = sposn; ctl[1] = ctl[7]; ctl[2] = ne ? gidx : SEQ;
        ctl[10] = validArr[sposn] ? 0 : 1;
        ctl[11] = (bch != 0) ? 1 : 0;
      }
    }
    __syncthreads();
  }
}

extern "C" void kernel_launch(void* const* d_in, const int* in_sizes, int n_in,
                              void* d_out, int out_size, void* d_ws, size_t ws_size,
                              hipStream_t stream){
  (void)in_sizes; (void)n_in; (void)out_size; (void)ws_size;
  const int*   tokens    = (const int*)  d_in[0];
  const float* word_emb  = (const float*)d_in[1];
  const float* compose_W = (const float*)d_in[2];
  const float* compose_b = (const float*)d_in[3];
  const float* h0        = (const float*)d_in[4];
  const float* c0        = (const float*)d_in[5];
  const float* pb_Wih    = (const float*)d_in[6];
  const float* pb_Whh    = (const float*)d_in[7];
  const float* pb_bih    = (const float*)d_in[8];
  const float* pb_bhh    = (const float*)d_in[9];
  const float* st_Wih    = (const float*)d_in[10];
  const float* st_Whh    = (const float*)d_in[11];
  const float* st_bih    = (const float*)d_in[12];
  const float* st_bhh    = (const float*)d_in[13];
  const float* hist_Wih  = (const float*)d_in[14];
  const float* hist_Whh  = (const float*)d_in[15];
  const float* hist_bih  = (const float*)d_in[16];
  const float* hist_bhh  = (const float*)d_in[17];
  const float* sum_W     = (const float*)d_in[18];
  const float* sum_b     = (const float*)d_in[19];
  const float* act_W     = (const float*)d_in[20];
  const float* act_b     = (const float*)d_in[21];
  const float* action_emb= (const float*)d_in[22];
  const int*   stack_map = (const int*)  d_in[23];
  const int*   buffer_map= (const int*)  d_in[24];

  float* ws = (float*)d_ws;
  // region0: pb_zx during P0/P1, then product caches (aliased)
  float*  pb_zx  = ws;                                         // NB*SEQ*G4
  float*  stzc   = ws;                                         // NB*S1*G4 (alias)
  double* sumsc  = (double*)(ws + (size_t)NB*S1*G4);           // NB*S1*H doubles (alias)
  float*  st_zx  = ws    + (size_t)NB*SEQ*G4;                  // NB*65*G4
  float*  bufh   = st_zx + (size_t)NB*(SEQ+1)*G4;              // NB*SEQ*H
  float*  scst   = bufh  + (size_t)NB*SEQ*H;                   // NB*S1*H
  float*  sth_g  = scst  + (size_t)NB*S1*H;                    // NB*S1*H
  float*  histxz = sth_g + (size_t)NB*S1*H;                    // NA*G4
  float*  Wt_pb  = histxz+ (size_t)NA*G4;                      // [256][1024]
  float*  Wt_st  = Wt_pb + (size_t)H*G4;
  float*  Wt_hi  = Wt_st + (size_t)H*G4;
  float*  Wt_sum = Wt_hi + (size_t)H*G4;                       // [768][256]
  float*  Wt_act = Wt_sum+ (size_t)768*H;                      // [256][64]
  float*  Wt_pbih= Wt_act+ (size_t)H*NA;                       // [128][1024]
  float*  Wt_stih= Wt_pbih+(size_t)DIN*G4;                     // [128][1024]
  float*  Wt_cmp = Wt_stih+(size_t)DIN*G4;                     // [256][128]

  dim3 blk(32, 8);
  transpose_k<<<dim3(256/32, 1024/32), blk, 0, stream>>>(pb_Whh,   Wt_pb,  1024, 256);
  transpose_k<<<dim3(256/32, 1024/32), blk, 0, stream>>>(st_Whh,   Wt_st,  1024, 256);
  transpose_k<<<dim3(256/32, 1024/32), blk, 0, stream>>>(hist_Whh, Wt_hi,  1024, 256);
  transpose_k<<<dim3(768/32,  256/32), blk, 0, stream>>>(sum_W,    Wt_sum,  256, 768);
  transpose_k<<<dim3(256/32,   64/32), blk, 0, stream>>>(act_W,    Wt_act,   64, 256);
  transpose_k<<<dim3(128/32, 1024/32), blk, 0, stream>>>(pb_Wih,   Wt_pbih,1024, 128);
  transpose_k<<<dim3(128/32, 1024/32), blk, 0, stream>>>(st_Wih,   Wt_stih,1024, 128);
  transpose_k<<<dim3(256/32,  128/32), blk, 0, stream>>>(compose_W,Wt_cmp,  128, 256);
  hist_proj_kernel<<<dim3(NA), dim3(256), 0, stream>>>(hist_Wih, hist_bih, hist_bhh,
                                                       action_emb, histxz);

  parser_kernel<<<dim3(NB), dim3(512), 0, stream>>>(tokens, word_emb, Wt_cmp, compose_b,
      h0, c0, Wt_pbih, Wt_pb, pb_bih, pb_bhh, Wt_stih, Wt_st, st_bih, st_bhh,
      Wt_hi, Wt_sum, sum_b, Wt_act, act_b, stack_map, buffer_map,
      histxz, pb_zx, stzc, sumsc, st_zx, bufh, scst, sth_g, (float*)d_out);
}